// Round 1
// baseline (127.450 us; speedup 1.0000x reference)
//
#include <hip/hip_runtime.h>

#define IN_F  4096
#define OUT_F 32000

typedef __attribute__((ext_vector_type(8))) short bf16x8;
typedef __attribute__((ext_vector_type(4))) float f32x4;

// fp32 -> bf16 round-to-nearest-even (finite inputs only)
__device__ __forceinline__ short bf_rne(float f) {
    unsigned u = __float_as_uint(f);
    return (short)((u + 0x7FFFu + ((u >> 16) & 1u)) >> 16);
}
// int (|w| <= 128) -> bf16, exact, truncation suffices
__device__ __forceinline__ short bf_int(int w) {
    return (short)(__float_as_uint((float)w) >> 16);
}

// One wave computes a 16(out-ch) x 16(batch) tile: D = W_tile * X^T.
// MFMA 16x16x32 bf16. K permuted per-call so each lane loads 16 contiguous
// weights (one dwordx4 of int32) per 2 MFMAs; A and B use the same k map.
__global__ __launch_bounds__(256) void w8a16_mfma_kernel(
    const int* __restrict__ W, const float* __restrict__ X,
    const float* __restrict__ scale, const float* __restrict__ bias,
    float* __restrict__ out)
{
    const int lane = threadIdx.x & 63;
    const int wave = threadIdx.x >> 6;
    const int n    = lane & 15;   // A row (out-ch offset) and B col (batch)
    const int kg   = lane >> 4;   // k-group 0..3
    const int o_base = blockIdx.x * 64 + wave * 16;

    const int*   Wrow = W + (size_t)(o_base + n) * IN_F + kg * 16;
    const float* Xrow = X + n * IN_F + kg * 16;

    f32x4 acc = {0.f, 0.f, 0.f, 0.f};

    #pragma unroll 2
    for (int k0 = 0; k0 < IN_F; k0 += 64) {
        const int4 w0 = *reinterpret_cast<const int4*>(Wrow + k0);
        const int4 w1 = *reinterpret_cast<const int4*>(Wrow + k0 + 4);
        const int4 w2 = *reinterpret_cast<const int4*>(Wrow + k0 + 8);
        const int4 w3 = *reinterpret_cast<const int4*>(Wrow + k0 + 12);
        const float4 x0 = *reinterpret_cast<const float4*>(Xrow + k0);
        const float4 x1 = *reinterpret_cast<const float4*>(Xrow + k0 + 4);
        const float4 x2 = *reinterpret_cast<const float4*>(Xrow + k0 + 8);
        const float4 x3 = *reinterpret_cast<const float4*>(Xrow + k0 + 12);

        bf16x8 a0, a1, b0, b1;
        a0[0]=bf_int(w0.x); a0[1]=bf_int(w0.y); a0[2]=bf_int(w0.z); a0[3]=bf_int(w0.w);
        a0[4]=bf_int(w1.x); a0[5]=bf_int(w1.y); a0[6]=bf_int(w1.z); a0[7]=bf_int(w1.w);
        a1[0]=bf_int(w2.x); a1[1]=bf_int(w2.y); a1[2]=bf_int(w2.z); a1[3]=bf_int(w2.w);
        a1[4]=bf_int(w3.x); a1[5]=bf_int(w3.y); a1[6]=bf_int(w3.z); a1[7]=bf_int(w3.w);
        b0[0]=bf_rne(x0.x); b0[1]=bf_rne(x0.y); b0[2]=bf_rne(x0.z); b0[3]=bf_rne(x0.w);
        b0[4]=bf_rne(x1.x); b0[5]=bf_rne(x1.y); b0[6]=bf_rne(x1.z); b0[7]=bf_rne(x1.w);
        b1[0]=bf_rne(x2.x); b1[1]=bf_rne(x2.y); b1[2]=bf_rne(x2.z); b1[3]=bf_rne(x2.w);
        b1[4]=bf_rne(x3.x); b1[5]=bf_rne(x3.y); b1[6]=bf_rne(x3.z); b1[7]=bf_rne(x3.w);

        acc = __builtin_amdgcn_mfma_f32_16x16x32_bf16(a0, b0, acc, 0, 0, 0);
        acc = __builtin_amdgcn_mfma_f32_16x16x32_bf16(a1, b1, acc, 0, 0, 0);
    }

    // C/D layout: col = lane&15 (batch), row = (lane>>4)*4 + reg (out-ch)
    const int o = o_base + kg * 4;
    const float4 sc = *reinterpret_cast<const float4*>(scale + o);
    const float4 bs = *reinterpret_cast<const float4*>(bias + o);
    float4 r;
    r.x = acc[0] * sc.x + bs.x;
    r.y = acc[1] * sc.y + bs.y;
    r.z = acc[2] * sc.z + bs.z;
    r.w = acc[3] * sc.w + bs.w;
    *reinterpret_cast<float4*>(out + (size_t)n * OUT_F + o) = r;
}

extern "C" void kernel_launch(void* const* d_in, const int* in_sizes, int n_in,
                              void* d_out, int out_size, void* d_ws, size_t ws_size,
                              hipStream_t stream) {
    const float* x     = (const float*)d_in[0];
    const int*   w     = (const int*)  d_in[1];   // int8 values widened to int32 by harness
    const float* scale = (const float*)d_in[2];
    const float* bias  = (const float*)d_in[3];
    float* out = (float*)d_out;
    (void)in_sizes; (void)n_in; (void)d_ws; (void)ws_size; (void)out_size;

    w8a16_mfma_kernel<<<dim3(OUT_F / 64), dim3(256), 0, stream>>>(w, x, scale, bias, out);
}

// Round 2
// 125.105 us; speedup vs baseline: 1.0187x; 1.0187x over previous
//
#include <hip/hip_runtime.h>

#define IN_F  4096
#define OUT_F 32000

typedef __attribute__((ext_vector_type(8))) short bf16x8;
typedef __attribute__((ext_vector_type(4))) float f32x4;

// float -> bf16 bits via native cast (hardware RNE on gfx950; compiler can
// pair these into v_cvt_pk_bf16_f32)
__device__ __forceinline__ short bf(float f) {
    __bf16 h = (__bf16)f;
    short s;
    __builtin_memcpy(&s, &h, 2);
    return s;
}

// One wave computes a 16(out-ch) x 16(batch) tile: D = W_tile * X^T via
// mfma_f32_16x16x32_bf16, K-loop over 4096 in chunks of 64.
//
// k->lane mapping (valid: A and B use the identical per-slot k permutation):
// load instruction i (i=0..3) has lane (n=lane&15, kg=lane>>4) read 4 values
// at k = k0 + i*16 + kg*4. So per instruction the 4 kg-lanes of each row
// cover one contiguous 64-B aligned block -> 16 segments x 64 B per wave
// instruction (vs 64 x 16 B before), and consecutive instructions reuse the
// same 128-B lines immediately.
__global__ __launch_bounds__(256) void w8a16_mfma_kernel(
    const int* __restrict__ W, const float* __restrict__ X,
    const float* __restrict__ scale, const float* __restrict__ bias,
    float* __restrict__ out)
{
    const int lane = threadIdx.x & 63;
    const int wave = threadIdx.x >> 6;
    const int n    = lane & 15;   // A row (out-ch offset) and B col (batch)
    const int kg   = lane >> 4;   // 16-B slot within each 64-B block
    const int o_base = blockIdx.x * 64 + wave * 16;

    const int*   Wrow = W + (size_t)(o_base + n) * IN_F + kg * 4;
    const float* Xrow = X + (size_t)n * IN_F + kg * 4;

    f32x4 acc = {0.f, 0.f, 0.f, 0.f};

    #pragma unroll 2
    for (int k0 = 0; k0 < IN_F; k0 += 64) {
        // instruction i covers k = k0 + i*16 + kg*4 + {0..3}
        const int4 w0 = *reinterpret_cast<const int4*>(Wrow + k0);
        const int4 w1 = *reinterpret_cast<const int4*>(Wrow + k0 + 16);
        const int4 w2 = *reinterpret_cast<const int4*>(Wrow + k0 + 32);
        const int4 w3 = *reinterpret_cast<const int4*>(Wrow + k0 + 48);
        const float4 x0 = *reinterpret_cast<const float4*>(Xrow + k0);
        const float4 x1 = *reinterpret_cast<const float4*>(Xrow + k0 + 16);
        const float4 x2 = *reinterpret_cast<const float4*>(Xrow + k0 + 32);
        const float4 x3 = *reinterpret_cast<const float4*>(Xrow + k0 + 48);

        bf16x8 a0, a1, b0, b1;
        a0[0]=bf((float)w0.x); a0[1]=bf((float)w0.y); a0[2]=bf((float)w0.z); a0[3]=bf((float)w0.w);
        a0[4]=bf((float)w1.x); a0[5]=bf((float)w1.y); a0[6]=bf((float)w1.z); a0[7]=bf((float)w1.w);
        a1[0]=bf((float)w2.x); a1[1]=bf((float)w2.y); a1[2]=bf((float)w2.z); a1[3]=bf((float)w2.w);
        a1[4]=bf((float)w3.x); a1[5]=bf((float)w3.y); a1[6]=bf((float)w3.z); a1[7]=bf((float)w3.w);
        b0[0]=bf(x0.x); b0[1]=bf(x0.y); b0[2]=bf(x0.z); b0[3]=bf(x0.w);
        b0[4]=bf(x1.x); b0[5]=bf(x1.y); b0[6]=bf(x1.z); b0[7]=bf(x1.w);
        b1[0]=bf(x2.x); b1[1]=bf(x2.y); b1[2]=bf(x2.z); b1[3]=bf(x2.w);
        b1[4]=bf(x3.x); b1[5]=bf(x3.y); b1[6]=bf(x3.z); b1[7]=bf(x3.w);

        acc = __builtin_amdgcn_mfma_f32_16x16x32_bf16(a0, b0, acc, 0, 0, 0);
        acc = __builtin_amdgcn_mfma_f32_16x16x32_bf16(a1, b1, acc, 0, 0, 0);
    }

    // C/D layout: col = lane&15 (batch), row = (lane>>4)*4 + reg (out-ch)
    const int o = o_base + kg * 4;
    const float4 sc = *reinterpret_cast<const float4*>(scale + o);
    const float4 bs = *reinterpret_cast<const float4*>(bias + o);
    float4 r;
    r.x = acc[0] * sc.x + bs.x;
    r.y = acc[1] * sc.y + bs.y;
    r.z = acc[2] * sc.z + bs.z;
    r.w = acc[3] * sc.w + bs.w;
    *reinterpret_cast<float4*>(out + (size_t)n * OUT_F + o) = r;
}

extern "C" void kernel_launch(void* const* d_in, const int* in_sizes, int n_in,
                              void* d_out, int out_size, void* d_ws, size_t ws_size,
                              hipStream_t stream) {
    const float* x     = (const float*)d_in[0];
    const int*   w     = (const int*)  d_in[1];   // int8 values widened to int32 by harness
    const float* scale = (const float*)d_in[2];
    const float* bias  = (const float*)d_in[3];
    float* out = (float*)d_out;
    (void)in_sizes; (void)n_in; (void)d_ws; (void)ws_size; (void)out_size;

    w8a16_mfma_kernel<<<dim3(OUT_F / 64), dim3(256), 0, stream>>>(w, x, scale, bias, out);
}

// Round 3
// 101.483 us; speedup vs baseline: 1.2559x; 1.2328x over previous
//
#include <hip/hip_runtime.h>

#define IN_F  4096
#define OUT_F 32000
#define KC    128          // k per tile
#define NT    (IN_F / KC)  // 32 tiles

typedef __attribute__((ext_vector_type(8))) short bf16x8;
typedef __attribute__((ext_vector_type(4))) float f32x4;

__device__ __forceinline__ short bf(float f) {
    __bf16 h = (__bf16)f;
    short s;
    __builtin_memcpy(&s, &h, 2);
    return s;
}

// Block = 256 threads (4 waves) computes 64 output channels x 16 batch.
// Per k-tile (KC=128): stage W[64][128] int32->bf16 and X[16][128] f32->bf16
// into XOR-swizzled LDS via contiguous 512-B row-chunk loads (8 fully-used
// lines per instr, no L1 set aliasing), then MFMA 16x16x32 from LDS.
// Double-buffered, one __syncthreads per tile; global loads for tile t+1
// issue before COMPUTE(t) so HBM latency hides under MFMA (T14 split).
__global__ __launch_bounds__(256) void w8a16_kernel(
    const int* __restrict__ W, const float* __restrict__ X,
    const float* __restrict__ scale, const float* __restrict__ bias,
    float* __restrict__ out)
{
    __shared__ __align__(16) short Wl[2][64][KC];  // 32 KB, swizzled rows (256 B)
    __shared__ __align__(16) short Xl[2][16][KC];  //  8 KB, swizzled rows

    const int tid  = threadIdx.x;
    const int lane = tid & 63;
    const int wave = tid >> 6;
    const int n    = lane & 15;   // MFMA: A row / B row (batch)
    const int kg   = lane >> 4;   // MFMA k-group
    const int lo   = lane & 31;   // staging: k-quad within 512-B chunk
    const int hi   = lane >> 5;   // staging: row parity within instr
    const int o_base = blockIdx.x * 64;

    int4   wreg[8];
    float4 xreg[2];
    f32x4  acc = {0.f, 0.f, 0.f, 0.f};

    // ---- staging helpers (explicit unroll; all indices compile-time) ----
    #define LOAD_TILE(t)                                                          \
        _Pragma("unroll")                                                         \
        for (int j = 0; j < 8; ++j) {                                             \
            const int r = wave * 16 + 2 * j + hi;                                 \
            wreg[j] = *reinterpret_cast<const int4*>(                             \
                W + (size_t)(o_base + r) * IN_F + (t) * KC + lo * 4);             \
        }                                                                         \
        _Pragma("unroll")                                                         \
        for (int j = 0; j < 2; ++j) {                                             \
            const int r = wave * 4 + 2 * j + hi;                                  \
            xreg[j] = *reinterpret_cast<const float4*>(                           \
                X + (size_t)r * IN_F + (t) * KC + lo * 4);                        \
        }

    #define CVT_WRITE(buf)                                                        \
        _Pragma("unroll")                                                         \
        for (int j = 0; j < 8; ++j) {                                             \
            const int r = wave * 16 + 2 * j + hi;                                 \
            short4 v;                                                             \
            v.x = bf((float)wreg[j].x); v.y = bf((float)wreg[j].y);               \
            v.z = bf((float)wreg[j].z); v.w = bf((float)wreg[j].w);               \
            char* p = (char*)&Wl[buf][r][0] + ((lo * 8) ^ ((r & 7) << 4));        \
            *reinterpret_cast<short4*>(p) = v;                                    \
        }                                                                         \
        _Pragma("unroll")                                                         \
        for (int j = 0; j < 2; ++j) {                                             \
            const int r = wave * 4 + 2 * j + hi;                                  \
            short4 v;                                                             \
            v.x = bf(xreg[j].x); v.y = bf(xreg[j].y);                             \
            v.z = bf(xreg[j].z); v.w = bf(xreg[j].w);                             \
            char* p = (char*)&Xl[buf][r][0] + ((lo * 8) ^ ((r & 7) << 4));        \
            *reinterpret_cast<short4*>(p) = v;                                    \
        }

    const int rA  = wave * 16 + n;
    const int swzA = (n & 7) << 4;   // same row->xor on write and read (involution)

    #define COMPUTE(buf)                                                          \
        _Pragma("unroll")                                                         \
        for (int s = 0; s < KC / 32; ++s) {                                       \
            const int off = (s * 64 + kg * 16) ^ swzA;                            \
            bf16x8 a = *reinterpret_cast<const bf16x8*>(                          \
                (const char*)&Wl[buf][rA][0] + off);                              \
            bf16x8 b = *reinterpret_cast<const bf16x8*>(                          \
                (const char*)&Xl[buf][n][0] + off);                               \
            acc = __builtin_amdgcn_mfma_f32_16x16x32_bf16(a, b, acc, 0, 0, 0);    \
        }

    // ---- prologue: tile 0 ----
    LOAD_TILE(0);
    CVT_WRITE(0);
    __syncthreads();

    // ---- main loop: one barrier per tile ----
    for (int t = 0; t < NT; ++t) {
        const int cur = t & 1;
        if (t + 1 < NT) { LOAD_TILE(t + 1); }     // issue early (in flight across COMPUTE)
        COMPUTE(cur);
        if (t + 1 < NT) { CVT_WRITE(cur ^ 1); }   // write late, other buffer
        __syncthreads();
    }

    // ---- epilogue: D col = lane&15 (batch n), row = kg*4 + reg (out-ch) ----
    const int o = o_base + wave * 16 + kg * 4;
    const float4 sc = *reinterpret_cast<const float4*>(scale + o);
    const float4 bs = *reinterpret_cast<const float4*>(bias + o);
    float4 rr;
    rr.x = acc[0] * sc.x + bs.x;
    rr.y = acc[1] * sc.y + bs.y;
    rr.z = acc[2] * sc.z + bs.z;
    rr.w = acc[3] * sc.w + bs.w;
    *reinterpret_cast<float4*>(out + (size_t)n * OUT_F + o) = rr;

    #undef LOAD_TILE
    #undef CVT_WRITE
    #undef COMPUTE
}

extern "C" void kernel_launch(void* const* d_in, const int* in_sizes, int n_in,
                              void* d_out, int out_size, void* d_ws, size_t ws_size,
                              hipStream_t stream) {
    const float* x     = (const float*)d_in[0];
    const int*   w     = (const int*)  d_in[1];   // int8 values widened to int32 by harness
    const float* scale = (const float*)d_in[2];
    const float* bias  = (const float*)d_in[3];
    float* out = (float*)d_out;
    (void)in_sizes; (void)n_in; (void)d_ws; (void)ws_size; (void)out_size;

    w8a16_kernel<<<dim3(OUT_F / 64), dim3(256), 0, stream>>>(w, x, scale, bias, out);
}

// Round 4
// 100.564 us; speedup vs baseline: 1.2673x; 1.0091x over previous
//
#include <hip/hip_runtime.h>

#define IN_F  4096
#define OUT_F 32000
#define KC    128          // k per tile
#define NT    (IN_F / KC)  // 32 tiles

typedef __attribute__((ext_vector_type(8))) short bf16x8;
typedef __attribute__((ext_vector_type(4))) float f32x4;

__device__ __forceinline__ short bf(float f) {
    __bf16 h = (__bf16)f;
    short s;
    __builtin_memcpy(&s, &h, 2);
    return s;
}

// Block = 256 threads (4 waves) computes 64 output channels x 16 batch.
// Depth-2 register prefetch: two k-tiles of global loads in flight per wave
// (wregA/wregB statically named), so outstanding VMEM never drains to zero;
// the wait before each CVT_WRITE covers loads issued a full tile earlier
// (compiler-counted vmcnt), not the just-issued ones. LDS double-buffered,
// XOR-swizzled, one barrier per tile.
__global__ __launch_bounds__(256) void w8a16_kernel(
    const int* __restrict__ W, const float* __restrict__ X,
    const float* __restrict__ scale, const float* __restrict__ bias,
    float* __restrict__ out)
{
    __shared__ __align__(16) short Wl[2][64][KC];  // 32 KB
    __shared__ __align__(16) short Xl[2][16][KC];  //  8 KB

    const int tid  = threadIdx.x;
    const int lane = tid & 63;
    const int wave = tid >> 6;
    const int n    = lane & 15;   // MFMA: A row (out-ch) / B row (batch)
    const int kg   = lane >> 4;   // MFMA k-group
    const int lo   = lane & 31;   // staging: 16-B quad within 512-B chunk
    const int hi   = lane >> 5;   // staging: row parity within instr
    const int o_base = blockIdx.x * 64;

    int4   wregA[8], wregB[8];
    float4 xregA[2], xregB[2];
    f32x4  acc = {0.f, 0.f, 0.f, 0.f};

    #define LOADR(WR, XR, t)                                                      \
        _Pragma("unroll")                                                         \
        for (int j = 0; j < 8; ++j) {                                             \
            const int r = wave * 16 + 2 * j + hi;                                 \
            WR[j] = *reinterpret_cast<const int4*>(                               \
                W + (size_t)(o_base + r) * IN_F + (t) * KC + lo * 4);             \
        }                                                                         \
        _Pragma("unroll")                                                         \
        for (int j = 0; j < 2; ++j) {                                             \
            const int r = wave * 4 + 2 * j + hi;                                  \
            XR[j] = *reinterpret_cast<const float4*>(                             \
                X + (size_t)r * IN_F + (t) * KC + lo * 4);                        \
        }

    #define CVT_WRITE(WR, XR, buf)                                               \
        _Pragma("unroll")                                                         \
        for (int j = 0; j < 8; ++j) {                                             \
            const int r = wave * 16 + 2 * j + hi;                                 \
            short4 v;                                                             \
            v.x = bf((float)WR[j].x); v.y = bf((float)WR[j].y);                   \
            v.z = bf((float)WR[j].z); v.w = bf((float)WR[j].w);                   \
            char* p = (char*)&Wl[buf][r][0] + ((lo * 8) ^ ((r & 7) << 4));        \
            *reinterpret_cast<short4*>(p) = v;                                    \
        }                                                                         \
        _Pragma("unroll")                                                         \
        for (int j = 0; j < 2; ++j) {                                             \
            const int r = wave * 4 + 2 * j + hi;                                  \
            short4 v;                                                             \
            v.x = bf(XR[j].x); v.y = bf(XR[j].y);                                 \
            v.z = bf(XR[j].z); v.w = bf(XR[j].w);                                 \
            char* p = (char*)&Xl[buf][r][0] + ((lo * 8) ^ ((r & 7) << 4));        \
            *reinterpret_cast<short4*>(p) = v;                                    \
        }

    const int rA   = wave * 16 + n;
    const int swzA = (n & 7) << 4;

    #define COMPUTE(buf)                                                          \
        _Pragma("unroll")                                                         \
        for (int s = 0; s < KC / 32; ++s) {                                       \
            const int off = (s * 64 + kg * 16) ^ swzA;                            \
            bf16x8 a = *reinterpret_cast<const bf16x8*>(                          \
                (const char*)&Wl[buf][rA][0] + off);                              \
            bf16x8 b = *reinterpret_cast<const bf16x8*>(                          \
                (const char*)&Xl[buf][n][0] + off);                               \
            acc = __builtin_amdgcn_mfma_f32_16x16x32_bf16(a, b, acc, 0, 0, 0);    \
        }

    // ---- prologue: tiles 0,1 in flight; write tile 0 ----
    LOADR(wregA, xregA, 0);
    LOADR(wregB, xregB, 1);
    CVT_WRITE(wregA, xregA, 0);   // waits only on tile-0 loads (oldest)
    __syncthreads();

    // ---- main loop, unrolled x2 for static A/B role swap ----
    for (int t = 0; t < NT; t += 2) {
        // even tile t: LDS[0] holds tile t
        if (t + 2 < NT) { LOADR(wregA, xregA, t + 2); }
        COMPUTE(0);
        if (t + 1 < NT) { CVT_WRITE(wregB, xregB, 1); }  // waits on tile t+1 loads
        __syncthreads();
        // odd tile t+1: LDS[1] holds tile t+1
        if (t + 3 < NT) { LOADR(wregB, xregB, t + 3); }
        COMPUTE(1);
        if (t + 2 < NT) { CVT_WRITE(wregA, xregA, 0); }  // waits on tile t+2 loads
        __syncthreads();
    }

    // ---- epilogue: D col = lane&15 (batch n), row = kg*4 + reg (out-ch) ----
    const int o = o_base + wave * 16 + kg * 4;
    const float4 sc = *reinterpret_cast<const float4*>(scale + o);
    const float4 bs = *reinterpret_cast<const float4*>(bias + o);
    float4 rr;
    rr.x = acc[0] * sc.x + bs.x;
    rr.y = acc[1] * sc.y + bs.y;
    rr.z = acc[2] * sc.z + bs.z;
    rr.w = acc[3] * sc.w + bs.w;
    *reinterpret_cast<float4*>(out + (size_t)n * OUT_F + o) = rr;

    #undef LOADR
    #undef CVT_WRITE
    #undef COMPUTE
}

extern "C" void kernel_launch(void* const* d_in, const int* in_sizes, int n_in,
                              void* d_out, int out_size, void* d_ws, size_t ws_size,
                              hipStream_t stream) {
    const float* x     = (const float*)d_in[0];
    const int*   w     = (const int*)  d_in[1];   // int8 values widened to int32 by harness
    const float* scale = (const float*)d_in[2];
    const float* bias  = (const float*)d_in[3];
    float* out = (float*)d_out;
    (void)in_sizes; (void)n_in; (void)d_ws; (void)ws_size; (void)out_size;

    w8a16_kernel<<<dim3(OUT_F / 64), dim3(256), 0, stream>>>(w, x, scale, bias, out);
}